// Round 1
// baseline (242.732 us; speedup 1.0000x reference)
//
#include <hip/hip_runtime.h>

// ConvexSampler: out = [ concat(z, s*z[a]+(1-s)*z[b]) ; labels(+oos) ; data_type(+1.0) ]
// B=16384, D=2048, NCONV=50. Pure memory-bound: ~258 MiB HBM traffic.

#define B_ROWS 16384
#define D_COLS 2048
#define NCONV  50
#define D4     (D_COLS / 4)          // 512 float4 per row

__global__ __launch_bounds__(256) void convex_sampler_kernel(
    const float* __restrict__ z,
    const int*   __restrict__ label_ids,
    const float* __restrict__ data_type,
    const int*   __restrict__ pair_idx,
    const float* __restrict__ s,
    const int*   __restrict__ oos_label_id,
    float*       __restrict__ out)
{
    // Unified flat work space (all fit comfortably in int32):
    const int NZ4   = B_ROWS * D4;            // 8,388,608 float4 copy items
    const int NC4   = NCONV * D4;             //    25,600 convex float4 items
    const int NR    = B_ROWS + NCONV;         //    16,434 rows out
    const int NTAIL = 2 * NR;                 //    32,868 scalar tail items
    const int total = NZ4 + NC4 + NTAIL;

    const float4* __restrict__ z4   = (const float4*)z;
    float4*       __restrict__ out4 = (float4*)out;

    const int stride = gridDim.x * blockDim.x;
    for (int i = blockIdx.x * blockDim.x + threadIdx.x; i < total; i += stride) {
        if (i < NZ4) {
            // Bulk copy of z -> z_out[0:B], fully coalesced 16B/lane.
            out4[i] = z4[i];
        } else if (i < NZ4 + NC4) {
            // Convex rows: out row (B + r) = s[r]*z[a] + (1-s[r])*z[b]
            int j   = i - NZ4;
            int r   = j / D4;      // convex row 0..49
            int c4  = j % D4;      // float4 column
            int ia  = pair_idx[2 * r];
            int ib  = pair_idx[2 * r + 1];
            float sv = s[r];
            float tv = 1.0f - sv;
            float4 a = z4[ia * D4 + c4];
            float4 b = z4[ib * D4 + c4];
            float4 rr;
            rr.x = sv * a.x + tv * b.x;
            rr.y = sv * a.y + tv * b.y;
            rr.z = sv * a.z + tv * b.z;
            rr.w = sv * a.w + tv * b.w;
            out4[NZ4 + j] = rr;    // z_out rows B..B+49 immediately follow the copy
        } else {
            // Scalar tails: labels_out then data_type_out, after (B+50)*D floats.
            int t = i - (NZ4 + NC4);
            const int base = NR * D_COLS;  // 16434*2048 = 33,656,832
            if (t < NR) {
                float v = (t < B_ROWS) ? (float)label_ids[t]
                                       : (float)(*oos_label_id);
                out[base + t] = v;
            } else {
                int u = t - NR;
                float v = (u < B_ROWS) ? data_type[u] : 1.0f;
                out[base + NR + u] = v;
            }
        }
    }
}

extern "C" void kernel_launch(void* const* d_in, const int* in_sizes, int n_in,
                              void* d_out, int out_size, void* d_ws, size_t ws_size,
                              hipStream_t stream) {
    const float* z          = (const float*)d_in[0];
    const int*   label_ids  = (const int*)  d_in[1];
    const float* data_type  = (const float*)d_in[2];
    const int*   pair_idx   = (const int*)  d_in[3];
    const float* s          = (const float*)d_in[4];
    const int*   oos        = (const int*)  d_in[5];
    float*       out        = (float*)d_out;

    // Memory-bound: ~2048 blocks x 256 threads, grid-stride (~16 float4/thread).
    dim3 grid(2048), block(256);
    hipLaunchKernelGGL(convex_sampler_kernel, grid, block, 0, stream,
                       z, label_ids, data_type, pair_idx, s, oos, out);
}